// Round 13
// baseline (199.929 us; speedup 1.0000x reference)
//
#include <hip/hip_runtime.h>
#include <math.h>

#define BSZ 8
#define NN 10000
#define DD 256
#define EE 160000
#define KK 5
#define BCAP 64
#define NROW (BSZ*NN)
#define AGGB 2500          // k_aggred blocks; 2500 * 4 waves * 2 iters * 2 half-pairs = 40000 pairs

typedef __attribute__((ext_vector_type(8))) short short8;
typedef __attribute__((ext_vector_type(4))) float f32x4;

// ---------- edge_index readers (int32 vs int64 storage, device-detected) ----------
__device__ __forceinline__ int e_row(const int* ei, int f64, int e){
    return f64 ? ei[2*e] : ei[e];
}
__device__ __forceinline__ int e_col(const int* ei, int f64, int e){
    return f64 ? ei[2*(EE+e)] : ei[EE+e];
}

// ---------- bf16 helpers (manual RNE) ----------
__device__ __forceinline__ unsigned short f2bf(float f){
    unsigned u = __float_as_uint(f);
    u += 0x7FFFu + ((u >> 16) & 1u);
    return (unsigned short)(u >> 16);
}
__device__ __forceinline__ float bflo(unsigned u){ return __uint_as_float(u << 16); }
__device__ __forceinline__ float bfhi(unsigned u){ return __uint_as_float(u & 0xFFFF0000u); }
__device__ __forceinline__ float dot4(float4 a, float4 b){
    return a.x*b.x + a.y*b.y + a.z*b.z + a.w*b.w;
}

// ---------- setup: pack lin_w to MFMA B-frag order + zero fill/reducers + detect ----------
// Bpack[nt][ks][lane][i] = bf16(lin_w[n][k]), n = nt*16+(lane&15), k = ks*32+(lane>>4)*8+i
__global__ void k_setup(const float* __restrict__ lin_w, unsigned short* __restrict__ Bpack,
                        const int* __restrict__ ei, int* __restrict__ fill,
                        int* __restrict__ flag, double* __restrict__ redL,
                        unsigned long long* __restrict__ redC, unsigned* __restrict__ ticket){
    const int blk = blockIdx.x;
    if (blk < 32){
        int t = blk*256 + threadIdx.x;   // 8192 = 16nt * 8ks * 64lane
        int l = t & 63, ks = (t>>6)&7, nt = t>>9;
        int n  = nt*16 + (l&15);
        int k0 = ks*32 + (l>>4)*8;
        const float* src = &lin_w[(size_t)n*DD + k0];
        ushort4 o0, o1;
        o0.x=f2bf(src[0]); o0.y=f2bf(src[1]); o0.z=f2bf(src[2]); o0.w=f2bf(src[3]);
        o1.x=f2bf(src[4]); o1.y=f2bf(src[5]); o1.z=f2bf(src[6]); o1.w=f2bf(src[7]);
        *(ushort4*)&Bpack[(size_t)t*8]     = o0;
        *(ushort4*)&Bpack[(size_t)t*8 + 4] = o1;
    } else {
        int t = (blk-32)*256 + threadIdx.x;
        if (t < NN) fill[t] = 0;
        if (t == 0){
            int all0 = 1;
            for (int i = 0; i < 32; ++i) if (ei[2*i+1] != 0) all0 = 0;
            *flag = all0;   // 1 => data is int64, read low words
        }
        if (t == 1){ *redL = 0.0; }
        if (t == 2){ *redC = 0ull; }
        if (t == 3){ *ticket = 0u; }
    }
}

// Stage (col, weight, eid) per row so top-k never re-reads edge_index.
__global__ void k_fill(const int* __restrict__ ei, const float* __restrict__ ew,
                       const int* __restrict__ flag,
                       int* __restrict__ fill, int* __restrict__ bc,
                       float* __restrict__ bw, int* __restrict__ be){
    int e = blockIdx.x*blockDim.x + threadIdx.x;
    if (e >= EE) return;
    int f = *flag;
    int r = e_row(ei, f, e);
    int c = e_col(ei, f, e);
    int pos = atomicAdd(&fill[r], 1);
    if (pos < BCAP){
        bc[r*BCAP + pos] = c;
        bw[r*BCAP + pos] = ew[e];
        be[r*BCAP + pos] = e;
    }
}

// One WAVE per row: dedup (max eid wins per (r,c) = numpy last-write-wins),
// drop diagonal edges and w<=0, rank by (w desc, c asc) = lax.top_k order.
__global__ __launch_bounds__(256) void k_top5(
    const int* __restrict__ fill, const int* __restrict__ bc,
    const float* __restrict__ bw, const int* __restrict__ be,
    int* __restrict__ nbr_idx, int* __restrict__ nbr_cnt)
{
    const int wave = threadIdx.x >> 6, lane = threadIdx.x & 63;
    const int r = blockIdx.x*4 + wave;
    if (r >= NN) return;
    int cnt = fill[r]; if (cnt > BCAP) cnt = BCAP;

    int c = -1, e = -1; float w = 0.f;
    if (lane < cnt){
        c = bc[r*BCAP + lane];
        w = bw[r*BCAP + lane];
        e = be[r*BCAP + lane];
    }
    bool alive = (lane < cnt) && (c != r) && (w > 0.f);

    for (int j = 0; j < cnt; ++j){
        const int cj = __shfl(c, j, 64);
        const int ej = __shfl(e, j, 64);
        if (cj == c && ej > e) alive = false;
    }
    int rank = 0;
    const int av = alive ? 1 : 0;
    for (int j = 0; j < cnt; ++j){
        const int   aj = __shfl(av, j, 64);
        const float wj = __shfl(w,  j, 64);
        const int   cj = __shfl(c,  j, 64);
        if (aj && (wj > w || (wj == w && cj < c))) ++rank;
    }
    const int want = lane - 1;
    int val = r;
    for (int j = 0; j < cnt; ++j){
        const int aj = __shfl(av,   j, 64);
        const int rj = __shfl(rank, j, 64);
        const int cj = __shfl(c,    j, 64);
        if (aj && rj == want && rj < 4) val = cj;
    }
    if (lane < KK) nbr_idx[r*KK + lane] = val;
    if (lane == 0){
        const int na = __popcll(__ballot(alive));
        nbr_cnt[r] = 1 + (na < 4 ? na : 4);
    }
}

// ---------- fused prep + dense GEMM (round-8/11 proven config):
// S = z1·sa_w + b ; Y = bf16(z1) @ lin_w^T. 4 waves share one 64x260 A-tile.
// Wave w owns 64 output cols (nt = 4w..4w+3) x all 64 rows. 31% occupancy is
// NOT the limiter (round 12: 66% occ at BM32 was slower) — keep this shape.
__global__ __launch_bounds__(256, 4) void k_gemmS(
    const float* __restrict__ z1,
    const float* __restrict__ sa_w, const float* __restrict__ sa_bp,
    const unsigned short* __restrict__ Bpack,
    float* __restrict__ S, unsigned short* __restrict__ Y)
{
    __shared__ __align__(16) unsigned short tileA[64][260];  // stride 520B: conflict-free A reads

    const int tid = threadIdx.x, wave = tid >> 6, lane = tid & 63;
    const int r0 = blockIdx.x*64;
    const int rw = r0 + wave*16;            // this wave stages rows rw..rw+15

    // stage 1: all 16 row-loads issued up-front (one vmcnt batch), then S + bf16 tile
    {
        const float4 sw = *(const float4*)&sa_w[lane*4];
        const float sab = *sa_bp;
        float4 v[16];
        #pragma unroll
        for (int rl = 0; rl < 16; ++rl)
            v[rl] = *(const float4*)&z1[(size_t)(rw+rl)*DD + lane*4];
        #pragma unroll
        for (int rl = 0; rl < 16; ++rl){
            float p = dot4(v[rl], sw);
            #pragma unroll
            for (int o = 32; o > 0; o >>= 1) p += __shfl_xor(p, o, 64);
            if (lane == 0) S[rw+rl] = p + sab;
            ushort4 u;
            u.x = f2bf(v[rl].x); u.y = f2bf(v[rl].y);
            u.z = f2bf(v[rl].z); u.w = f2bf(v[rl].w);
            *(ushort4*)&tileA[wave*16 + rl][lane*4] = u;
        }
    }
    __syncthreads();

    // stage 2: 16x16x32 MFMA. A: row=lane&15, k=(lane>>4)*8+i ;
    // C/D: col=lane&15, row=(lane>>4)*4+reg. acc[rf][nj], nt = wave*4+nj.
    const unsigned short* aBase = &tileA[lane & 15][(lane >> 4) * 8];
    const short8* bPtr = (const short8*)Bpack + lane;
    f32x4 acc[4][4];
    #pragma unroll
    for (int rf = 0; rf < 4; ++rf)
        #pragma unroll
        for (int nj = 0; nj < 4; ++nj) acc[rf][nj] = (f32x4){0.f,0.f,0.f,0.f};

    #pragma unroll
    for (int ks = 0; ks < 8; ++ks){
        short8 bfr[4];
        #pragma unroll
        for (int nj = 0; nj < 4; ++nj)
            bfr[nj] = bPtr[((wave*4 + nj)*8 + ks)*64];
        #pragma unroll
        for (int rf = 0; rf < 4; ++rf){
            const short8 a = *(const short8*)(aBase + rf*16*260 + ks*32);
            #pragma unroll
            for (int nj = 0; nj < 4; ++nj)
                acc[rf][nj] = __builtin_amdgcn_mfma_f32_16x16x32_bf16(a, bfr[nj], acc[rf][nj], 0, 0, 0);
        }
    }

    // store raw Y (no bias/norm here; bias folds through the attention sum)
    #pragma unroll
    for (int rf = 0; rf < 4; ++rf){
        const int rowBase = r0 + rf*16 + (lane >> 4)*4;
        #pragma unroll
        for (int nj = 0; nj < 4; ++nj){
            const int col = (wave*4 + nj)*16 + (lane & 15);
            #pragma unroll
            for (int reg = 0; reg < 4; ++reg)
                Y[(size_t)(rowBase + reg)*DD + col] = f2bf(acc[rf][nj][reg]);
        }
    }
}

// ---------- pair-fused softmax + gather + loss + final reduce ----------
// sigma(b,n) = (b^1, (n+5000)%NN) is a fixed-point-free involution.
// Softmax in-place (8-lane group shfl reduce); pair per half-wave; block
// partials merged by device-scope f64/u64 atomics; ticket's last block
// reads totals back via atomicAdd(·,0) (coherent) and writes out[0..1].
__global__ __launch_bounds__(256) void k_aggred(
    const float* __restrict__ z2, const unsigned short* __restrict__ Y,
    const float* __restrict__ S,
    const int* __restrict__ nbr_idx, const int* __restrict__ nbr_cnt,
    const float* __restrict__ lin_b,
    double* __restrict__ redL, unsigned long long* __restrict__ redC,
    unsigned* __restrict__ ticket, float* __restrict__ out)
{
    const int tid = threadIdx.x;
    const int wave = tid >> 6, lane = tid & 63;
    const int half = lane >> 5, hl = lane & 31;
    const int gw = blockIdx.x*4 + wave;          // 0..9999
    const int cb = hl*8;                         // this lane's 8-col slice
    const float4 lba = *(const float4*)&lin_b[cb];
    const float4 lbb = *(const float4*)&lin_b[cb+4];
    double lacc = 0.0;
    int cacc = 0;

    #pragma unroll 1
    for (int j = 0; j < 2; ++j){
        const int p  = gw*4 + j*2 + half;        // 0..39999, unique per half-wave
        const int bb = p / NN, n0 = p % NN;
        const int b0 = 2*bb, b1 = b0 + 1;
        int n1 = n0 + 5000; if (n1 >= NN) n1 -= NN;
        const size_t r0 = (size_t)b0*NN + n0;
        const size_t r1 = (size_t)b1*NN + n1;

        // in-place softmax: hl 0-7 = row0 slots, hl 8-15 = row1 slots
        const int cnt0 = nbr_cnt[n0], cnt1 = nbr_cnt[n1];
        float sv = -1e9f;
        if (hl < 8){
            if (hl < cnt0) sv = S[b0*NN + nbr_idx[n0*KK + hl]];
        } else if (hl < 16){
            const int k2 = hl - 8;
            if (k2 < cnt1) sv = S[b1*NN + nbr_idx[n1*KK + k2]];
        }
        float mx = sv;
        #pragma unroll
        for (int o = 1; o < 8; o <<= 1) mx = fmaxf(mx, __shfl_xor(mx, o, 64));
        const float ev = __expf(sv - mx);
        float sm = ev;
        #pragma unroll
        for (int o = 1; o < 8; o <<= 1) sm += __shfl_xor(sm, o, 64);
        const float av = ev / sm;                // softmax weight on slot lanes

        float4 h0a = lba, h0b = lbb, h1a = lba, h1b = lbb;
        #pragma unroll
        for (int k = 0; k < KK; ++k){
            const int i0 = nbr_idx[n0*KK + k];
            const int i1 = nbr_idx[n1*KK + k];
            const float a0 = __shfl(av, half*32 + k, 64);
            const float a1 = __shfl(av, half*32 + 8 + k, 64);
            const uint4 u0 = *(const uint4*)&Y[((size_t)(b0*NN) + i0)*DD + cb];
            const uint4 u1 = *(const uint4*)&Y[((size_t)(b1*NN) + i1)*DD + cb];
            h0a.x = fmaf(a0, bflo(u0.x), h0a.x); h0a.y = fmaf(a0, bfhi(u0.x), h0a.y);
            h0a.z = fmaf(a0, bflo(u0.y), h0a.z); h0a.w = fmaf(a0, bfhi(u0.y), h0a.w);
            h0b.x = fmaf(a0, bflo(u0.z), h0b.x); h0b.y = fmaf(a0, bfhi(u0.z), h0b.y);
            h0b.z = fmaf(a0, bflo(u0.w), h0b.z); h0b.w = fmaf(a0, bfhi(u0.w), h0b.w);
            h1a.x = fmaf(a1, bflo(u1.x), h1a.x); h1a.y = fmaf(a1, bfhi(u1.x), h1a.y);
            h1a.z = fmaf(a1, bflo(u1.y), h1a.z); h1a.w = fmaf(a1, bfhi(u1.y), h1a.w);
            h1b.x = fmaf(a1, bflo(u1.z), h1b.x); h1b.y = fmaf(a1, bfhi(u1.z), h1b.y);
            h1b.z = fmaf(a1, bflo(u1.w), h1b.z); h1b.w = fmaf(a1, bfhi(u1.w), h1b.w);
        }
        const float4 s0a = *(const float4*)&z2[r0*DD + cb];
        const float4 s0b = *(const float4*)&z2[r0*DD + cb + 4];
        const float4 s1a = *(const float4*)&z2[r1*DD + cb];
        const float4 s1b = *(const float4*)&z2[r1*DD + cb + 4];

        float d0 = dot4(s0a,s0a) + dot4(s0b,s0b);
        float d1 = dot4(s1a,s1a) + dot4(s1b,s1b);
        float d2 = dot4(h0a,h0a) + dot4(h0b,h0b);
        float d3 = dot4(h1a,h1a) + dot4(h1b,h1b);
        float d4 = dot4(s0a,h0a) + dot4(s0b,h0b);
        float d5 = dot4(s1a,h1a) + dot4(s1b,h1b);
        float d6 = dot4(s0a,h1a) + dot4(s0b,h1b);
        float d7 = dot4(s1a,h0a) + dot4(s1b,h0b);
        #pragma unroll
        for (int o = 1; o < 32; o <<= 1){        // 5-step butterfly within the half
            d0 += __shfl_xor(d0, o, 64);
            d1 += __shfl_xor(d1, o, 64);
            d2 += __shfl_xor(d2, o, 64);
            d3 += __shfl_xor(d3, o, 64);
            d4 += __shfl_xor(d4, o, 64);
            d5 += __shfl_xor(d5, o, 64);
            d6 += __shfl_xor(d6, o, 64);
            d7 += __shfl_xor(d7, o, 64);
        }
        // hl 0: x0=d4/sqrt(d0*d2) real ; hl 1: x1=d5/sqrt(d1*d3) real
        // hl 2: y0=d6/sqrt(d0*d3) fake ; hl 3: y1=d7/sqrt(d1*d2) fake
        const float num = hl==1 ? d5 : (hl==2 ? d6 : (hl==3 ? d7 : d4));
        const float den = hl==1 ? d1*d3 : (hl==2 ? d0*d3 : (hl==3 ? d1*d2 : d0*d2));
        if (hl < 4){
            const bool real = (hl < 2);
            const float x = num * rsqrtf(den);
            const float z = __expf(-fabsf(x));            // |x|<=1 -> z in [0.37,1]
            const float l = fmaxf(x, 0.f) - (real ? x : 0.f) + __logf(1.f + z);
            lacc += (double)l;
            cacc += real ? (x > 0.f ? 1 : 0) : (x > 0.f ? 0 : 1);
        }
    }
    // reduce lanes {0-3} and {32-35} -> lane 0
    lacc += __shfl_xor(lacc, 1, 64);
    lacc += __shfl_xor(lacc, 2, 64);
    lacc += __shfl_xor(lacc, 32, 64);
    cacc += __shfl_xor(cacc, 1, 64);
    cacc += __shfl_xor(cacc, 2, 64);
    cacc += __shfl_xor(cacc, 32, 64);

    __shared__ double sl[4];
    __shared__ int scn[4];
    if (lane == 0){ sl[wave] = lacc; scn[wave] = cacc; }
    __syncthreads();
    if (tid == 0){
        const double Lb = sl[0]+sl[1]+sl[2]+sl[3];
        const unsigned long long Cb =
            (unsigned long long)(scn[0]+scn[1]+scn[2]+scn[3]);
        atomicAdd(redL, Lb);
        atomicAdd(redC, Cb);
        __threadfence();
        const unsigned t = atomicAdd(ticket, 1u);
        if (t == AGGB - 1){
            const double L = atomicAdd(redL, 0.0);                 // coherent read
            const unsigned long long C = atomicAdd(redC, 0ull);    // coherent read
            const double denom = 2.0 * BSZ * NN;   // 160000
            out[0] = (float)(L / denom);
            out[1] = (float)((double)C / denom);
        }
    }
}

// ---------- host ----------
extern "C" void kernel_launch(void* const* d_in, const int* in_sizes, int n_in,
                              void* d_out, int out_size, void* d_ws, size_t ws_size,
                              hipStream_t stream)
{
    (void)in_sizes; (void)n_in; (void)out_size; (void)ws_size;
    const float* z1    = (const float*)d_in[0];
    const float* z2    = (const float*)d_in[1];
    const int*   ei    = (const int*)d_in[2];
    const float* ew    = (const float*)d_in[3];
    const float* sa_w  = (const float*)d_in[4];
    const float* sa_b  = (const float*)d_in[5];
    const float* lin_w = (const float*)d_in[6];
    const float* lin_b = (const float*)d_in[7];
    float* out = (float*)d_out;

    char* ws = (char*)d_ws;
    size_t off = 0;
    auto take = [&](size_t bytes) -> char* {
        char* p = ws + off;
        off = (off + bytes + 255) & ~(size_t)255;
        return p;
    };
    int*                flag    = (int*)take(4);
    double*             redL    = (double*)take(8);
    unsigned long long* redC    = (unsigned long long*)take(8);
    unsigned*           ticket  = (unsigned*)take(4);
    int*                fill    = (int*)take((size_t)NN*4);
    int*                nbr_idx = (int*)take((size_t)NN*KK*4);
    int*                nbr_cnt = (int*)take((size_t)NN*4);
    unsigned short*     Bpack   = (unsigned short*)take((size_t)16*8*64*8*2);
    float*              S       = (float*)take((size_t)NROW*4);
    // buckets live only until k_top5; Y overlays them afterwards (stream-ordered)
    const size_t bucket_off = off;
    int*                bc      = (int*)take((size_t)NN*BCAP*4);
    float*              bw      = (float*)take((size_t)NN*BCAP*4);
    int*                be      = (int*)take((size_t)NN*BCAP*4);
    off = bucket_off;
    unsigned short*     Y       = (unsigned short*)take((size_t)NROW*DD*2);

    k_setup <<<72,            256, 0, stream>>>(lin_w, Bpack, ei, fill, flag,
                                                redL, redC, ticket);
    k_fill  <<<(EE+255)/256,  256, 0, stream>>>(ei, ew, flag, fill, bc, bw, be);
    k_top5  <<<(NN+3)/4,      256, 0, stream>>>(fill, bc, bw, be, nbr_idx, nbr_cnt);
    k_gemmS <<<NROW/64,       256, 0, stream>>>(z1, sa_w, sa_b, Bpack, S, Y);
    k_aggred<<<AGGB,          256, 0, stream>>>(z2, Y, S, nbr_idx, nbr_cnt, lin_b,
                                                redL, redC, ticket, out);
}

// Round 14
// 124.885 us; speedup vs baseline: 1.6009x; 1.6009x over previous
//
#include <hip/hip_runtime.h>
#include <math.h>

#define BSZ 8
#define NN 10000
#define DD 256
#define EE 160000
#define KK 5
#define BCAP 64
#define NROW (BSZ*NN)
#define AGGB 2500          // k_aggred blocks; 2500 * 4 waves * 2 iters * 2 half-pairs = 40000 pairs

typedef __attribute__((ext_vector_type(8))) short short8;
typedef __attribute__((ext_vector_type(4))) float f32x4;

// ---------- edge_index readers (int32 vs int64 storage, device-detected) ----------
__device__ __forceinline__ int e_row(const int* ei, int f64, int e){
    return f64 ? ei[2*e] : ei[e];
}
__device__ __forceinline__ int e_col(const int* ei, int f64, int e){
    return f64 ? ei[2*(EE+e)] : ei[EE+e];
}

// ---------- bf16 helpers (manual RNE) ----------
__device__ __forceinline__ unsigned short f2bf(float f){
    unsigned u = __float_as_uint(f);
    u += 0x7FFFu + ((u >> 16) & 1u);
    return (unsigned short)(u >> 16);
}
__device__ __forceinline__ float bflo(unsigned u){ return __uint_as_float(u << 16); }
__device__ __forceinline__ float bfhi(unsigned u){ return __uint_as_float(u & 0xFFFF0000u); }
__device__ __forceinline__ float dot4(float4 a, float4 b){
    return a.x*b.x + a.y*b.y + a.z*b.z + a.w*b.w;
}

// ---------- setup: pack lin_w to MFMA B-frag order + zero fill + detect ----------
// Bpack[nt][ks][lane][i] = bf16(lin_w[n][k]), n = nt*16+(lane&15), k = ks*32+(lane>>4)*8+i
__global__ void k_setup(const float* __restrict__ lin_w, unsigned short* __restrict__ Bpack,
                        const int* __restrict__ ei, int* __restrict__ fill,
                        int* __restrict__ flag){
    const int blk = blockIdx.x;
    if (blk < 32){
        int t = blk*256 + threadIdx.x;   // 8192 = 16nt * 8ks * 64lane
        int l = t & 63, ks = (t>>6)&7, nt = t>>9;
        int n  = nt*16 + (l&15);
        int k0 = ks*32 + (l>>4)*8;
        const float* src = &lin_w[(size_t)n*DD + k0];
        ushort4 o0, o1;
        o0.x=f2bf(src[0]); o0.y=f2bf(src[1]); o0.z=f2bf(src[2]); o0.w=f2bf(src[3]);
        o1.x=f2bf(src[4]); o1.y=f2bf(src[5]); o1.z=f2bf(src[6]); o1.w=f2bf(src[7]);
        *(ushort4*)&Bpack[(size_t)t*8]     = o0;
        *(ushort4*)&Bpack[(size_t)t*8 + 4] = o1;
    } else {
        int t = (blk-32)*256 + threadIdx.x;
        if (t < NN) fill[t] = 0;
        if (t == 0){
            int all0 = 1;
            for (int i = 0; i < 32; ++i) if (ei[2*i+1] != 0) all0 = 0;
            *flag = all0;   // 1 => data is int64, read low words
        }
    }
}

// Stage (col, weight, eid) per row, packed as one int4 (single 16B store).
__global__ void k_fill(const int* __restrict__ ei, const float* __restrict__ ew,
                       const int* __restrict__ flag,
                       int* __restrict__ fill, int4* __restrict__ bkt){
    int e = blockIdx.x*blockDim.x + threadIdx.x;
    if (e >= EE) return;
    int f = *flag;
    int r = e_row(ei, f, e);
    int c = e_col(ei, f, e);
    int pos = atomicAdd(&fill[r], 1);
    if (pos < BCAP){
        int4 v; v.x = c; v.y = __float_as_int(ew[e]); v.z = e; v.w = 0;
        bkt[r*BCAP + pos] = v;
    }
}

// One WAVE per row: dedup (max eid wins per (r,c) = numpy last-write-wins),
// drop diagonal edges and w<=0, rank by (w desc, c asc) = lax.top_k order.
__global__ __launch_bounds__(256) void k_top5(
    const int* __restrict__ fill, const int4* __restrict__ bkt,
    int* __restrict__ nbr_idx, int* __restrict__ nbr_cnt)
{
    const int wave = threadIdx.x >> 6, lane = threadIdx.x & 63;
    const int r = blockIdx.x*4 + wave;
    if (r >= NN) return;
    int cnt = fill[r]; if (cnt > BCAP) cnt = BCAP;

    int c = -1, e = -1; float w = 0.f;
    if (lane < cnt){
        const int4 v = bkt[r*BCAP + lane];
        c = v.x; w = __int_as_float(v.y); e = v.z;
    }
    bool alive = (lane < cnt) && (c != r) && (w > 0.f);

    for (int j = 0; j < cnt; ++j){
        const int cj = __shfl(c, j, 64);
        const int ej = __shfl(e, j, 64);
        if (cj == c && ej > e) alive = false;
    }
    int rank = 0;
    const int av = alive ? 1 : 0;
    for (int j = 0; j < cnt; ++j){
        const int   aj = __shfl(av, j, 64);
        const float wj = __shfl(w,  j, 64);
        const int   cj = __shfl(c,  j, 64);
        if (aj && (wj > w || (wj == w && cj < c))) ++rank;
    }
    const int want = lane - 1;
    int val = r;
    for (int j = 0; j < cnt; ++j){
        const int aj = __shfl(av,   j, 64);
        const int rj = __shfl(rank, j, 64);
        const int cj = __shfl(c,    j, 64);
        if (aj && rj == want && rj < 4) val = cj;
    }
    if (lane < KK) nbr_idx[r*KK + lane] = val;
    if (lane == 0){
        const int na = __popcll(__ballot(alive));
        nbr_cnt[r] = 1 + (na < 4 ? na : 4);
    }
}

// ---------- fused prep + dense GEMM (round-8/11 proven config):
// S = z1·sa_w + b ; Y = bf16(z1) @ lin_w^T. 4 waves share one 64x260 A-tile.
// Wave w owns 64 output cols (nt = 4w..4w+3) x all 64 rows. Single-buffered B
// (explicit dbuf spills, r10); 31% occupancy is NOT the limiter (r12: 66% occ
// at BM32 was slower); scattered Y stores don't amplify HBM writes (r8 PMC).
__global__ __launch_bounds__(256, 4) void k_gemmS(
    const float* __restrict__ z1,
    const float* __restrict__ sa_w, const float* __restrict__ sa_bp,
    const unsigned short* __restrict__ Bpack,
    float* __restrict__ S, unsigned short* __restrict__ Y)
{
    __shared__ __align__(16) unsigned short tileA[64][260];  // stride 520B: conflict-free A reads

    const int tid = threadIdx.x, wave = tid >> 6, lane = tid & 63;
    const int r0 = blockIdx.x*64;
    const int rw = r0 + wave*16;            // this wave stages rows rw..rw+15

    // stage 1: all 16 row-loads issued up-front (one vmcnt batch), then S + bf16 tile
    {
        const float4 sw = *(const float4*)&sa_w[lane*4];
        const float sab = *sa_bp;
        float4 v[16];
        #pragma unroll
        for (int rl = 0; rl < 16; ++rl)
            v[rl] = *(const float4*)&z1[(size_t)(rw+rl)*DD + lane*4];
        #pragma unroll
        for (int rl = 0; rl < 16; ++rl){
            float p = dot4(v[rl], sw);
            #pragma unroll
            for (int o = 32; o > 0; o >>= 1) p += __shfl_xor(p, o, 64);
            if (lane == 0) S[rw+rl] = p + sab;
            ushort4 u;
            u.x = f2bf(v[rl].x); u.y = f2bf(v[rl].y);
            u.z = f2bf(v[rl].z); u.w = f2bf(v[rl].w);
            *(ushort4*)&tileA[wave*16 + rl][lane*4] = u;
        }
    }
    __syncthreads();

    // stage 2: 16x16x32 MFMA. A: row=lane&15, k=(lane>>4)*8+i ;
    // C/D: col=lane&15, row=(lane>>4)*4+reg. acc[rf][nj], nt = wave*4+nj.
    const unsigned short* aBase = &tileA[lane & 15][(lane >> 4) * 8];
    const short8* bPtr = (const short8*)Bpack + lane;
    f32x4 acc[4][4];
    #pragma unroll
    for (int rf = 0; rf < 4; ++rf)
        #pragma unroll
        for (int nj = 0; nj < 4; ++nj) acc[rf][nj] = (f32x4){0.f,0.f,0.f,0.f};

    #pragma unroll
    for (int ks = 0; ks < 8; ++ks){
        short8 bfr[4];
        #pragma unroll
        for (int nj = 0; nj < 4; ++nj)
            bfr[nj] = bPtr[((wave*4 + nj)*8 + ks)*64];
        #pragma unroll
        for (int rf = 0; rf < 4; ++rf){
            const short8 a = *(const short8*)(aBase + rf*16*260 + ks*32);
            #pragma unroll
            for (int nj = 0; nj < 4; ++nj)
                acc[rf][nj] = __builtin_amdgcn_mfma_f32_16x16x32_bf16(a, bfr[nj], acc[rf][nj], 0, 0, 0);
        }
    }

    // store raw Y (no bias/norm here; bias folds through the attention sum)
    #pragma unroll
    for (int rf = 0; rf < 4; ++rf){
        const int rowBase = r0 + rf*16 + (lane >> 4)*4;
        #pragma unroll
        for (int nj = 0; nj < 4; ++nj){
            const int col = (wave*4 + nj)*16 + (lane & 15);
            #pragma unroll
            for (int reg = 0; reg < 4; ++reg)
                Y[(size_t)(rowBase + reg)*DD + col] = f2bf(acc[rf][nj][reg]);
        }
    }
}

// ---------- pair-fused softmax + gather + loss, one pair per HALF-wave ----------
// sigma(b,n) = (b^1, (n+5000)%NN) is a fixed-point-free involution.
// Softmax computed in-place: lanes hl 0-7 own row0's k-slots, hl 8-15 row1's
// (3-step shfl group-reduce); a_k broadcast by __shfl in the gather loop.
// Invalid k slots get exp(-1e9 - m) = 0 (exactly the reference NEG_INF mask).
// Block partials go to ARRAYS + a tiny k_final kernel — device-scope atomics
// + threadfence in this kernel collapse L2/BW on non-coherent XCDs (r13).
__global__ __launch_bounds__(256) void k_aggred(
    const float* __restrict__ z2, const unsigned short* __restrict__ Y,
    const float* __restrict__ S,
    const int* __restrict__ nbr_idx, const int* __restrict__ nbr_cnt,
    const float* __restrict__ lin_b,
    double* __restrict__ loss_part, long long* __restrict__ cnt_part)
{
    const int tid = threadIdx.x;
    const int wave = tid >> 6, lane = tid & 63;
    const int half = lane >> 5, hl = lane & 31;
    const int gw = blockIdx.x*4 + wave;          // 0..9999
    const int cb = hl*8;                         // this lane's 8-col slice
    const float4 lba = *(const float4*)&lin_b[cb];
    const float4 lbb = *(const float4*)&lin_b[cb+4];
    double lacc = 0.0;
    int cacc = 0;

    #pragma unroll 1
    for (int j = 0; j < 2; ++j){
        const int p  = gw*4 + j*2 + half;        // 0..39999, unique per half-wave
        const int bb = p / NN, n0 = p % NN;
        const int b0 = 2*bb, b1 = b0 + 1;
        int n1 = n0 + 5000; if (n1 >= NN) n1 -= NN;
        const size_t r0 = (size_t)b0*NN + n0;
        const size_t r1 = (size_t)b1*NN + n1;

        // in-place softmax: hl 0-7 = row0 slots, hl 8-15 = row1 slots
        const int cnt0 = nbr_cnt[n0], cnt1 = nbr_cnt[n1];
        float sv = -1e9f;
        if (hl < 8){
            if (hl < cnt0) sv = S[b0*NN + nbr_idx[n0*KK + hl]];
        } else if (hl < 16){
            const int k2 = hl - 8;
            if (k2 < cnt1) sv = S[b1*NN + nbr_idx[n1*KK + k2]];
        }
        float mx = sv;
        #pragma unroll
        for (int o = 1; o < 8; o <<= 1) mx = fmaxf(mx, __shfl_xor(mx, o, 64));
        const float ev = __expf(sv - mx);
        float sm = ev;
        #pragma unroll
        for (int o = 1; o < 8; o <<= 1) sm += __shfl_xor(sm, o, 64);
        const float av = ev / sm;                // softmax weight on slot lanes

        float4 h0a = lba, h0b = lbb, h1a = lba, h1b = lbb;
        #pragma unroll
        for (int k = 0; k < KK; ++k){
            const int i0 = nbr_idx[n0*KK + k];
            const int i1 = nbr_idx[n1*KK + k];
            const float a0 = __shfl(av, half*32 + k, 64);
            const float a1 = __shfl(av, half*32 + 8 + k, 64);
            const uint4 u0 = *(const uint4*)&Y[((size_t)(b0*NN) + i0)*DD + cb];
            const uint4 u1 = *(const uint4*)&Y[((size_t)(b1*NN) + i1)*DD + cb];
            h0a.x = fmaf(a0, bflo(u0.x), h0a.x); h0a.y = fmaf(a0, bfhi(u0.x), h0a.y);
            h0a.z = fmaf(a0, bflo(u0.y), h0a.z); h0a.w = fmaf(a0, bfhi(u0.y), h0a.w);
            h0b.x = fmaf(a0, bflo(u0.z), h0b.x); h0b.y = fmaf(a0, bfhi(u0.z), h0b.y);
            h0b.z = fmaf(a0, bflo(u0.w), h0b.z); h0b.w = fmaf(a0, bfhi(u0.w), h0b.w);
            h1a.x = fmaf(a1, bflo(u1.x), h1a.x); h1a.y = fmaf(a1, bfhi(u1.x), h1a.y);
            h1a.z = fmaf(a1, bflo(u1.y), h1a.z); h1a.w = fmaf(a1, bfhi(u1.y), h1a.w);
            h1b.x = fmaf(a1, bflo(u1.z), h1b.x); h1b.y = fmaf(a1, bfhi(u1.z), h1b.y);
            h1b.z = fmaf(a1, bflo(u1.w), h1b.z); h1b.w = fmaf(a1, bfhi(u1.w), h1b.w);
        }
        const float4 s0a = *(const float4*)&z2[r0*DD + cb];
        const float4 s0b = *(const float4*)&z2[r0*DD + cb + 4];
        const float4 s1a = *(const float4*)&z2[r1*DD + cb];
        const float4 s1b = *(const float4*)&z2[r1*DD + cb + 4];

        float d0 = dot4(s0a,s0a) + dot4(s0b,s0b);
        float d1 = dot4(s1a,s1a) + dot4(s1b,s1b);
        float d2 = dot4(h0a,h0a) + dot4(h0b,h0b);
        float d3 = dot4(h1a,h1a) + dot4(h1b,h1b);
        float d4 = dot4(s0a,h0a) + dot4(s0b,h0b);
        float d5 = dot4(s1a,h1a) + dot4(s1b,h1b);
        float d6 = dot4(s0a,h1a) + dot4(s0b,h1b);
        float d7 = dot4(s1a,h0a) + dot4(s1b,h0b);
        #pragma unroll
        for (int o = 1; o < 32; o <<= 1){        // 5-step butterfly within the half
            d0 += __shfl_xor(d0, o, 64);
            d1 += __shfl_xor(d1, o, 64);
            d2 += __shfl_xor(d2, o, 64);
            d3 += __shfl_xor(d3, o, 64);
            d4 += __shfl_xor(d4, o, 64);
            d5 += __shfl_xor(d5, o, 64);
            d6 += __shfl_xor(d6, o, 64);
            d7 += __shfl_xor(d7, o, 64);
        }
        // hl 0: x0=d4/sqrt(d0*d2) real ; hl 1: x1=d5/sqrt(d1*d3) real
        // hl 2: y0=d6/sqrt(d0*d3) fake ; hl 3: y1=d7/sqrt(d1*d2) fake
        const float num = hl==1 ? d5 : (hl==2 ? d6 : (hl==3 ? d7 : d4));
        const float den = hl==1 ? d1*d3 : (hl==2 ? d0*d3 : (hl==3 ? d1*d2 : d0*d2));
        if (hl < 4){
            const bool real = (hl < 2);
            const float x = num * rsqrtf(den);
            const float z = __expf(-fabsf(x));            // |x|<=1 -> z in [0.37,1]
            const float l = fmaxf(x, 0.f) - (real ? x : 0.f) + __logf(1.f + z);
            lacc += (double)l;
            cacc += real ? (x > 0.f ? 1 : 0) : (x > 0.f ? 0 : 1);
        }
    }
    // reduce lanes {0-3} and {32-35} -> lane 0
    lacc += __shfl_xor(lacc, 1, 64);
    lacc += __shfl_xor(lacc, 2, 64);
    lacc += __shfl_xor(lacc, 32, 64);
    cacc += __shfl_xor(cacc, 1, 64);
    cacc += __shfl_xor(cacc, 2, 64);
    cacc += __shfl_xor(cacc, 32, 64);

    __shared__ double sl[4];
    __shared__ int scn[4];
    if (lane == 0){ sl[wave] = lacc; scn[wave] = cacc; }
    __syncthreads();
    if (tid == 0){
        loss_part[blockIdx.x] = sl[0]+sl[1]+sl[2]+sl[3];
        cnt_part[blockIdx.x]  = (long long)scn[0] + scn[1] + scn[2] + scn[3];
    }
}

__global__ void k_final(const double* __restrict__ loss_part,
                        const long long* __restrict__ cnt_part,
                        float* __restrict__ out){
    __shared__ double sl[256];
    __shared__ long long sc[256];
    double l = 0.0; long long c = 0;
    for (int i = threadIdx.x; i < AGGB; i += 256){ l += loss_part[i]; c += cnt_part[i]; }
    sl[threadIdx.x] = l; sc[threadIdx.x] = c;
    __syncthreads();
    for (int s = 128; s > 0; s >>= 1){
        if (threadIdx.x < s){
            sl[threadIdx.x] += sl[threadIdx.x + s];
            sc[threadIdx.x] += sc[threadIdx.x + s];
        }
        __syncthreads();
    }
    if (threadIdx.x == 0){
        const double denom = 2.0 * BSZ * NN;   // 160000
        out[0] = (float)(sl[0] / denom);
        out[1] = (float)((double)sc[0] / denom);
    }
}

// ---------- host ----------
extern "C" void kernel_launch(void* const* d_in, const int* in_sizes, int n_in,
                              void* d_out, int out_size, void* d_ws, size_t ws_size,
                              hipStream_t stream)
{
    (void)in_sizes; (void)n_in; (void)out_size; (void)ws_size;
    const float* z1    = (const float*)d_in[0];
    const float* z2    = (const float*)d_in[1];
    const int*   ei    = (const int*)d_in[2];
    const float* ew    = (const float*)d_in[3];
    const float* sa_w  = (const float*)d_in[4];
    const float* sa_b  = (const float*)d_in[5];
    const float* lin_w = (const float*)d_in[6];
    const float* lin_b = (const float*)d_in[7];
    float* out = (float*)d_out;

    char* ws = (char*)d_ws;
    size_t off = 0;
    auto take = [&](size_t bytes) -> char* {
        char* p = ws + off;
        off = (off + bytes + 255) & ~(size_t)255;
        return p;
    };
    int*            flag      = (int*)take(4);
    int*            fill      = (int*)take((size_t)NN*4);
    int*            nbr_idx   = (int*)take((size_t)NN*KK*4);
    int*            nbr_cnt   = (int*)take((size_t)NN*4);
    unsigned short* Bpack     = (unsigned short*)take((size_t)16*8*64*8*2);
    float*          S         = (float*)take((size_t)NROW*4);
    double*         loss_part = (double*)take((size_t)AGGB*8);
    long long*      cnt_part  = (long long*)take((size_t)AGGB*8);
    // buckets live only until k_top5; Y overlays them afterwards (stream-ordered)
    const size_t bucket_off = off;
    int4*           bkt       = (int4*)take((size_t)NN*BCAP*16);
    off = bucket_off;
    unsigned short* Y         = (unsigned short*)take((size_t)NROW*DD*2);

    k_setup <<<72,            256, 0, stream>>>(lin_w, Bpack, ei, fill, flag);
    k_fill  <<<(EE+255)/256,  256, 0, stream>>>(ei, ew, flag, fill, bkt);
    k_top5  <<<(NN+3)/4,      256, 0, stream>>>(fill, bkt, nbr_idx, nbr_cnt);
    k_gemmS <<<NROW/64,       256, 0, stream>>>(z1, sa_w, sa_b, Bpack, S, Y);
    k_aggred<<<AGGB,          256, 0, stream>>>(z2, Y, S, nbr_idx, nbr_cnt, lin_b,
                                                loss_part, cnt_part);
    k_final <<<1,             256, 0, stream>>>(loss_part, cnt_part, out);
}

// Round 15
// 113.790 us; speedup vs baseline: 1.7570x; 1.0975x over previous
//
#include <hip/hip_runtime.h>
#include <math.h>

#define BSZ 8
#define NN 10000
#define DD 256
#define EE 160000
#define KK 5
#define BCAP 64
#define NROW (BSZ*NN)
#define AGGB 2500          // k_aggred blocks; 2500 * 4 waves * 2 iters * 2 half-pairs = 40000 pairs
#define GEMMB (NROW/64)    // 1250 gemm blocks in k_mega
#define FILLB ((EE+255)/256) // 625 fill blocks in k_mega

typedef __attribute__((ext_vector_type(8))) short short8;
typedef __attribute__((ext_vector_type(4))) float f32x4;

// ---------- edge_index readers (int32 vs int64 storage, device-detected) ----------
__device__ __forceinline__ int e_row(const int* ei, int f64, int e){
    return f64 ? ei[2*e] : ei[e];
}
__device__ __forceinline__ int e_col(const int* ei, int f64, int e){
    return f64 ? ei[2*(EE+e)] : ei[EE+e];
}

// ---------- bf16 helpers (manual RNE) ----------
__device__ __forceinline__ unsigned short f2bf(float f){
    unsigned u = __float_as_uint(f);
    u += 0x7FFFu + ((u >> 16) & 1u);
    return (unsigned short)(u >> 16);
}
__device__ __forceinline__ float bflo(unsigned u){ return __uint_as_float(u << 16); }
__device__ __forceinline__ float bfhi(unsigned u){ return __uint_as_float(u & 0xFFFF0000u); }
__device__ __forceinline__ float dot4(float4 a, float4 b){
    return a.x*b.x + a.y*b.y + a.z*b.z + a.w*b.w;
}

// ---------- setup: pack lin_w to MFMA B-frag order + zero fill + detect ----------
// Bpack[nt][ks][lane][i] = bf16(lin_w[n][k]), n = nt*16+(lane&15), k = ks*32+(lane>>4)*8+i
__global__ void k_setup(const float* __restrict__ lin_w, unsigned short* __restrict__ Bpack,
                        const int* __restrict__ ei, int* __restrict__ fill,
                        int* __restrict__ flag){
    const int blk = blockIdx.x;
    if (blk < 32){
        int t = blk*256 + threadIdx.x;   // 8192 = 16nt * 8ks * 64lane
        int l = t & 63, ks = (t>>6)&7, nt = t>>9;
        int n  = nt*16 + (l&15);
        int k0 = ks*32 + (l>>4)*8;
        const float* src = &lin_w[(size_t)n*DD + k0];
        ushort4 o0, o1;
        o0.x=f2bf(src[0]); o0.y=f2bf(src[1]); o0.z=f2bf(src[2]); o0.w=f2bf(src[3]);
        o1.x=f2bf(src[4]); o1.y=f2bf(src[5]); o1.z=f2bf(src[6]); o1.w=f2bf(src[7]);
        *(ushort4*)&Bpack[(size_t)t*8]     = o0;
        *(ushort4*)&Bpack[(size_t)t*8 + 4] = o1;
    } else {
        int t = (blk-32)*256 + threadIdx.x;
        if (t < NN) fill[t] = 0;
        if (t == 0){
            int all0 = 1;
            for (int i = 0; i < 32; ++i) if (ei[2*i+1] != 0) all0 = 0;
            *flag = all0;   // 1 => data is int64, read low words
        }
    }
}

// ---------- mega: dense GEMM tiles (blocks 0..GEMMB-1) + edge-bucket fill ----------
// The GEMM path is latency-bound with idle pipes (r14 PMC: VALU 11%, MFMA 7%,
// HBM 19%); the fill path (independent dataflow: edge data only) rides in its
// latency bubbles instead of serializing as a separate 8 us dispatch.
__global__ __launch_bounds__(256, 4) void k_mega(
    const float* __restrict__ z1,
    const float* __restrict__ sa_w, const float* __restrict__ sa_bp,
    const unsigned short* __restrict__ Bpack,
    float* __restrict__ S, unsigned short* __restrict__ Y,
    const int* __restrict__ ei, const float* __restrict__ ew,
    const int* __restrict__ flag, int* __restrict__ fill, int4* __restrict__ bkt)
{
    __shared__ __align__(16) unsigned short tileA[64][260];  // stride 520B: conflict-free A reads

    if (blockIdx.x >= GEMMB){
        // ---- fill path: stage (col, weight, eid) per row as one int4 store ----
        int e = (blockIdx.x - GEMMB)*256 + threadIdx.x;
        if (e < EE){
            int f = *flag;
            int r = e_row(ei, f, e);
            int c = e_col(ei, f, e);
            int pos = atomicAdd(&fill[r], 1);
            if (pos < BCAP){
                int4 v; v.x = c; v.y = __float_as_int(ew[e]); v.z = e; v.w = 0;
                bkt[r*BCAP + pos] = v;
            }
        }
        return;
    }

    // ---- GEMM path (round-8/11 proven config): S = z1·sa_w + b ; Y = bf16(z1) @ lin_w^T
    // 4 waves share one 64x260 A-tile; wave w owns 64 output cols x all 64 rows.
    // Single-buffered B (dbuf spills, r10); occupancy is not the limiter (r12).
    const int tid = threadIdx.x, wave = tid >> 6, lane = tid & 63;
    const int r0 = blockIdx.x*64;
    const int rw = r0 + wave*16;            // this wave stages rows rw..rw+15

    // stage 1: all 16 row-loads issued up-front (one vmcnt batch), then S + bf16 tile
    {
        const float4 sw = *(const float4*)&sa_w[lane*4];
        const float sab = *sa_bp;
        float4 v[16];
        #pragma unroll
        for (int rl = 0; rl < 16; ++rl)
            v[rl] = *(const float4*)&z1[(size_t)(rw+rl)*DD + lane*4];
        #pragma unroll
        for (int rl = 0; rl < 16; ++rl){
            float p = dot4(v[rl], sw);
            #pragma unroll
            for (int o = 32; o > 0; o >>= 1) p += __shfl_xor(p, o, 64);
            if (lane == 0) S[rw+rl] = p + sab;
            ushort4 u;
            u.x = f2bf(v[rl].x); u.y = f2bf(v[rl].y);
            u.z = f2bf(v[rl].z); u.w = f2bf(v[rl].w);
            *(ushort4*)&tileA[wave*16 + rl][lane*4] = u;
        }
    }
    __syncthreads();

    // stage 2: 16x16x32 MFMA. A: row=lane&15, k=(lane>>4)*8+i ;
    // C/D: col=lane&15, row=(lane>>4)*4+reg. acc[rf][nj], nt = wave*4+nj.
    const unsigned short* aBase = &tileA[lane & 15][(lane >> 4) * 8];
    const short8* bPtr = (const short8*)Bpack + lane;
    f32x4 acc[4][4];
    #pragma unroll
    for (int rf = 0; rf < 4; ++rf)
        #pragma unroll
        for (int nj = 0; nj < 4; ++nj) acc[rf][nj] = (f32x4){0.f,0.f,0.f,0.f};

    #pragma unroll
    for (int ks = 0; ks < 8; ++ks){
        short8 bfr[4];
        #pragma unroll
        for (int nj = 0; nj < 4; ++nj)
            bfr[nj] = bPtr[((wave*4 + nj)*8 + ks)*64];
        #pragma unroll
        for (int rf = 0; rf < 4; ++rf){
            const short8 a = *(const short8*)(aBase + rf*16*260 + ks*32);
            #pragma unroll
            for (int nj = 0; nj < 4; ++nj)
                acc[rf][nj] = __builtin_amdgcn_mfma_f32_16x16x32_bf16(a, bfr[nj], acc[rf][nj], 0, 0, 0);
        }
    }

    // store raw Y (no bias/norm here; bias folds through the attention sum)
    #pragma unroll
    for (int rf = 0; rf < 4; ++rf){
        const int rowBase = r0 + rf*16 + (lane >> 4)*4;
        #pragma unroll
        for (int nj = 0; nj < 4; ++nj){
            const int col = (wave*4 + nj)*16 + (lane & 15);
            #pragma unroll
            for (int reg = 0; reg < 4; ++reg)
                Y[(size_t)(rowBase + reg)*DD + col] = f2bf(acc[rf][nj][reg]);
        }
    }
}

// One WAVE per row: dedup (max eid wins per (r,c) = numpy last-write-wins),
// drop diagonal edges and w<=0, rank by (w desc, c asc) = lax.top_k order.
__global__ __launch_bounds__(256) void k_top5(
    const int* __restrict__ fill, const int4* __restrict__ bkt,
    int* __restrict__ nbr_idx, int* __restrict__ nbr_cnt)
{
    const int wave = threadIdx.x >> 6, lane = threadIdx.x & 63;
    const int r = blockIdx.x*4 + wave;
    if (r >= NN) return;
    int cnt = fill[r]; if (cnt > BCAP) cnt = BCAP;

    int c = -1, e = -1; float w = 0.f;
    if (lane < cnt){
        const int4 v = bkt[r*BCAP + lane];
        c = v.x; w = __int_as_float(v.y); e = v.z;
    }
    bool alive = (lane < cnt) && (c != r) && (w > 0.f);

    for (int j = 0; j < cnt; ++j){
        const int cj = __shfl(c, j, 64);
        const int ej = __shfl(e, j, 64);
        if (cj == c && ej > e) alive = false;
    }
    int rank = 0;
    const int av = alive ? 1 : 0;
    for (int j = 0; j < cnt; ++j){
        const int   aj = __shfl(av, j, 64);
        const float wj = __shfl(w,  j, 64);
        const int   cj = __shfl(c,  j, 64);
        if (aj && (wj > w || (wj == w && cj < c))) ++rank;
    }
    const int want = lane - 1;
    int val = r;
    for (int j = 0; j < cnt; ++j){
        const int aj = __shfl(av,   j, 64);
        const int rj = __shfl(rank, j, 64);
        const int cj = __shfl(c,    j, 64);
        if (aj && rj == want && rj < 4) val = cj;
    }
    if (lane < KK) nbr_idx[r*KK + lane] = val;
    if (lane == 0){
        const int na = __popcll(__ballot(alive));
        nbr_cnt[r] = 1 + (na < 4 ? na : 4);
    }
}

// ---------- pair-fused softmax + gather + loss, one pair per HALF-wave ----------
// sigma(b,n) = (b^1, (n+5000)%NN) is a fixed-point-free involution.
// Softmax computed in-place: lanes hl 0-7 own row0's k-slots, hl 8-15 row1's
// (3-step shfl group-reduce); a_k broadcast by __shfl in the gather loop.
// Invalid k slots get exp(-1e9 - m) = 0 (exactly the reference NEG_INF mask).
// Block partials go to ARRAYS + a tiny k_final kernel — device-scope atomics
// + threadfence in this kernel collapse L2/BW on non-coherent XCDs (r13).
__global__ __launch_bounds__(256) void k_aggred(
    const float* __restrict__ z2, const unsigned short* __restrict__ Y,
    const float* __restrict__ S,
    const int* __restrict__ nbr_idx, const int* __restrict__ nbr_cnt,
    const float* __restrict__ lin_b,
    double* __restrict__ loss_part, long long* __restrict__ cnt_part)
{
    const int tid = threadIdx.x;
    const int wave = tid >> 6, lane = tid & 63;
    const int half = lane >> 5, hl = lane & 31;
    const int gw = blockIdx.x*4 + wave;          // 0..9999
    const int cb = hl*8;                         // this lane's 8-col slice
    const float4 lba = *(const float4*)&lin_b[cb];
    const float4 lbb = *(const float4*)&lin_b[cb+4];
    double lacc = 0.0;
    int cacc = 0;

    #pragma unroll 1
    for (int j = 0; j < 2; ++j){
        const int p  = gw*4 + j*2 + half;        // 0..39999, unique per half-wave
        const int bb = p / NN, n0 = p % NN;
        const int b0 = 2*bb, b1 = b0 + 1;
        int n1 = n0 + 5000; if (n1 >= NN) n1 -= NN;
        const size_t r0 = (size_t)b0*NN + n0;
        const size_t r1 = (size_t)b1*NN + n1;

        // in-place softmax: hl 0-7 = row0 slots, hl 8-15 = row1 slots
        const int cnt0 = nbr_cnt[n0], cnt1 = nbr_cnt[n1];
        float sv = -1e9f;
        if (hl < 8){
            if (hl < cnt0) sv = S[b0*NN + nbr_idx[n0*KK + hl]];
        } else if (hl < 16){
            const int k2 = hl - 8;
            if (k2 < cnt1) sv = S[b1*NN + nbr_idx[n1*KK + k2]];
        }
        float mx = sv;
        #pragma unroll
        for (int o = 1; o < 8; o <<= 1) mx = fmaxf(mx, __shfl_xor(mx, o, 64));
        const float ev = __expf(sv - mx);
        float sm = ev;
        #pragma unroll
        for (int o = 1; o < 8; o <<= 1) sm += __shfl_xor(sm, o, 64);
        const float av = ev / sm;                // softmax weight on slot lanes

        float4 h0a = lba, h0b = lbb, h1a = lba, h1b = lbb;
        #pragma unroll
        for (int k = 0; k < KK; ++k){
            const int i0 = nbr_idx[n0*KK + k];
            const int i1 = nbr_idx[n1*KK + k];
            const float a0 = __shfl(av, half*32 + k, 64);
            const float a1 = __shfl(av, half*32 + 8 + k, 64);
            const uint4 u0 = *(const uint4*)&Y[((size_t)(b0*NN) + i0)*DD + cb];
            const uint4 u1 = *(const uint4*)&Y[((size_t)(b1*NN) + i1)*DD + cb];
            h0a.x = fmaf(a0, bflo(u0.x), h0a.x); h0a.y = fmaf(a0, bfhi(u0.x), h0a.y);
            h0a.z = fmaf(a0, bflo(u0.y), h0a.z); h0a.w = fmaf(a0, bfhi(u0.y), h0a.w);
            h0b.x = fmaf(a0, bflo(u0.z), h0b.x); h0b.y = fmaf(a0, bfhi(u0.z), h0b.y);
            h0b.z = fmaf(a0, bflo(u0.w), h0b.z); h0b.w = fmaf(a0, bfhi(u0.w), h0b.w);
            h1a.x = fmaf(a1, bflo(u1.x), h1a.x); h1a.y = fmaf(a1, bfhi(u1.x), h1a.y);
            h1a.z = fmaf(a1, bflo(u1.y), h1a.z); h1a.w = fmaf(a1, bfhi(u1.y), h1a.w);
            h1b.x = fmaf(a1, bflo(u1.z), h1b.x); h1b.y = fmaf(a1, bfhi(u1.z), h1b.y);
            h1b.z = fmaf(a1, bflo(u1.w), h1b.z); h1b.w = fmaf(a1, bfhi(u1.w), h1b.w);
        }
        const float4 s0a = *(const float4*)&z2[r0*DD + cb];
        const float4 s0b = *(const float4*)&z2[r0*DD + cb + 4];
        const float4 s1a = *(const float4*)&z2[r1*DD + cb];
        const float4 s1b = *(const float4*)&z2[r1*DD + cb + 4];

        float d0 = dot4(s0a,s0a) + dot4(s0b,s0b);
        float d1 = dot4(s1a,s1a) + dot4(s1b,s1b);
        float d2 = dot4(h0a,h0a) + dot4(h0b,h0b);
        float d3 = dot4(h1a,h1a) + dot4(h1b,h1b);
        float d4 = dot4(s0a,h0a) + dot4(s0b,h0b);
        float d5 = dot4(s1a,h1a) + dot4(s1b,h1b);
        float d6 = dot4(s0a,h1a) + dot4(s0b,h1b);
        float d7 = dot4(s1a,h0a) + dot4(s1b,h0b);
        #pragma unroll
        for (int o = 1; o < 32; o <<= 1){        // 5-step butterfly within the half
            d0 += __shfl_xor(d0, o, 64);
            d1 += __shfl_xor(d1, o, 64);
            d2 += __shfl_xor(d2, o, 64);
            d3 += __shfl_xor(d3, o, 64);
            d4 += __shfl_xor(d4, o, 64);
            d5 += __shfl_xor(d5, o, 64);
            d6 += __shfl_xor(d6, o, 64);
            d7 += __shfl_xor(d7, o, 64);
        }
        // hl 0: x0=d4/sqrt(d0*d2) real ; hl 1: x1=d5/sqrt(d1*d3) real
        // hl 2: y0=d6/sqrt(d0*d3) fake ; hl 3: y1=d7/sqrt(d1*d2) fake
        const float num = hl==1 ? d5 : (hl==2 ? d6 : (hl==3 ? d7 : d4));
        const float den = hl==1 ? d1*d3 : (hl==2 ? d0*d3 : (hl==3 ? d1*d2 : d0*d2));
        if (hl < 4){
            const bool real = (hl < 2);
            const float x = num * rsqrtf(den);
            const float z = __expf(-fabsf(x));            // |x|<=1 -> z in [0.37,1]
            const float l = fmaxf(x, 0.f) - (real ? x : 0.f) + __logf(1.f + z);
            lacc += (double)l;
            cacc += real ? (x > 0.f ? 1 : 0) : (x > 0.f ? 0 : 1);
        }
    }
    // reduce lanes {0-3} and {32-35} -> lane 0
    lacc += __shfl_xor(lacc, 1, 64);
    lacc += __shfl_xor(lacc, 2, 64);
    lacc += __shfl_xor(lacc, 32, 64);
    cacc += __shfl_xor(cacc, 1, 64);
    cacc += __shfl_xor(cacc, 2, 64);
    cacc += __shfl_xor(cacc, 32, 64);

    __shared__ double sl[4];
    __shared__ int scn[4];
    if (lane == 0){ sl[wave] = lacc; scn[wave] = cacc; }
    __syncthreads();
    if (tid == 0){
        loss_part[blockIdx.x] = sl[0]+sl[1]+sl[2]+sl[3];
        cnt_part[blockIdx.x]  = (long long)scn[0] + scn[1] + scn[2] + scn[3];
    }
}

__global__ void k_final(const double* __restrict__ loss_part,
                        const long long* __restrict__ cnt_part,
                        float* __restrict__ out){
    __shared__ double sl[256];
    __shared__ long long sc[256];
    double l = 0.0; long long c = 0;
    for (int i = threadIdx.x; i < AGGB; i += 256){ l += loss_part[i]; c += cnt_part[i]; }
    sl[threadIdx.x] = l; sc[threadIdx.x] = c;
    __syncthreads();
    for (int s = 128; s > 0; s >>= 1){
        if (threadIdx.x < s){
            sl[threadIdx.x] += sl[threadIdx.x + s];
            sc[threadIdx.x] += sc[threadIdx.x + s];
        }
        __syncthreads();
    }
    if (threadIdx.x == 0){
        const double denom = 2.0 * BSZ * NN;   // 160000
        out[0] = (float)(sl[0] / denom);
        out[1] = (float)((double)sc[0] / denom);
    }
}

// ---------- host ----------
extern "C" void kernel_launch(void* const* d_in, const int* in_sizes, int n_in,
                              void* d_out, int out_size, void* d_ws, size_t ws_size,
                              hipStream_t stream)
{
    (void)in_sizes; (void)n_in; (void)out_size; (void)ws_size;
    const float* z1    = (const float*)d_in[0];
    const float* z2    = (const float*)d_in[1];
    const int*   ei    = (const int*)d_in[2];
    const float* ew    = (const float*)d_in[3];
    const float* sa_w  = (const float*)d_in[4];
    const float* sa_b  = (const float*)d_in[5];
    const float* lin_w = (const float*)d_in[6];
    const float* lin_b = (const float*)d_in[7];
    float* out = (float*)d_out;

    char* ws = (char*)d_ws;
    size_t off = 0;
    auto take = [&](size_t bytes) -> char* {
        char* p = ws + off;
        off = (off + bytes + 255) & ~(size_t)255;
        return p;
    };
    int*            flag      = (int*)take(4);
    int*            fill      = (int*)take((size_t)NN*4);
    int*            nbr_idx   = (int*)take((size_t)NN*KK*4);
    int*            nbr_cnt   = (int*)take((size_t)NN*4);
    unsigned short* Bpack     = (unsigned short*)take((size_t)16*8*64*8*2);
    float*          S         = (float*)take((size_t)NROW*4);
    double*         loss_part = (double*)take((size_t)AGGB*8);
    long long*      cnt_part  = (long long*)take((size_t)AGGB*8);
    // bkt can NO LONGER overlay Y: fill and gemm now run concurrently in k_mega.
    int4*           bkt       = (int4*)take((size_t)NN*BCAP*16);   // 10.24 MB
    unsigned short* Y         = (unsigned short*)take((size_t)NROW*DD*2);  // 40.96 MB

    k_setup <<<72,            256, 0, stream>>>(lin_w, Bpack, ei, fill, flag);
    k_mega  <<<GEMMB + FILLB, 256, 0, stream>>>(z1, sa_w, sa_b, Bpack, S, Y,
                                                ei, ew, flag, fill, bkt);
    k_top5  <<<(NN+3)/4,      256, 0, stream>>>(fill, bkt, nbr_idx, nbr_cnt);
    k_aggred<<<AGGB,          256, 0, stream>>>(z2, Y, S, nbr_idx, nbr_cnt, lin_b,
                                                loss_part, cnt_part);
    k_final <<<1,             256, 0, stream>>>(loss_part, cnt_part, out);
}

// Round 16
// 111.865 us; speedup vs baseline: 1.7872x; 1.0172x over previous
//
#include <hip/hip_runtime.h>
#include <math.h>

#define BSZ 8
#define NN 10000
#define DD 256
#define EE 160000
#define KK 5
#define BCAP 64
#define NROW (BSZ*NN)
#define AGGB 2500          // k_aggred blocks; 2500 * 4 waves * 2 iters * 2 half-pairs = 40000 pairs
#define GEMMB (NROW/64)    // 1250 gemm blocks in k_mega
#define FILLB ((EE+255)/256) // 625 fill blocks in k_mega

typedef __attribute__((ext_vector_type(8))) short short8;
typedef __attribute__((ext_vector_type(4))) float f32x4;

// ---------- edge_index readers (int32 vs int64 storage, device-detected) ----------
__device__ __forceinline__ int e_row(const int* ei, int f64, int e){
    return f64 ? ei[2*e] : ei[e];
}
__device__ __forceinline__ int e_col(const int* ei, int f64, int e){
    return f64 ? ei[2*(EE+e)] : ei[EE+e];
}

// ---------- bf16 helpers (manual RNE) ----------
__device__ __forceinline__ unsigned short f2bf(float f){
    unsigned u = __float_as_uint(f);
    u += 0x7FFFu + ((u >> 16) & 1u);
    return (unsigned short)(u >> 16);
}
__device__ __forceinline__ float bflo(unsigned u){ return __uint_as_float(u << 16); }
__device__ __forceinline__ float bfhi(unsigned u){ return __uint_as_float(u & 0xFFFF0000u); }
__device__ __forceinline__ float dot4(float4 a, float4 b){
    return a.x*b.x + a.y*b.y + a.z*b.z + a.w*b.w;
}

// ---------- setup: pack lin_w to MFMA B-frag order + zero fill + detect ----------
// Bpack[nt][ks][lane][i] = bf16(lin_w[n][k]), n = nt*16+(lane&15), k = ks*32+(lane>>4)*8+i
__global__ void k_setup(const float* __restrict__ lin_w, unsigned short* __restrict__ Bpack,
                        const int* __restrict__ ei, int* __restrict__ fill,
                        int* __restrict__ flag){
    const int blk = blockIdx.x;
    if (blk < 32){
        int t = blk*256 + threadIdx.x;   // 8192 = 16nt * 8ks * 64lane
        int l = t & 63, ks = (t>>6)&7, nt = t>>9;
        int n  = nt*16 + (l&15);
        int k0 = ks*32 + (l>>4)*8;
        const float* src = &lin_w[(size_t)n*DD + k0];
        ushort4 o0, o1;
        o0.x=f2bf(src[0]); o0.y=f2bf(src[1]); o0.z=f2bf(src[2]); o0.w=f2bf(src[3]);
        o1.x=f2bf(src[4]); o1.y=f2bf(src[5]); o1.z=f2bf(src[6]); o1.w=f2bf(src[7]);
        *(ushort4*)&Bpack[(size_t)t*8]     = o0;
        *(ushort4*)&Bpack[(size_t)t*8 + 4] = o1;
    } else {
        int t = (blk-32)*256 + threadIdx.x;
        if (t < NN) fill[t] = 0;
        if (t == 0){
            int all0 = 1;
            for (int i = 0; i < 32; ++i) if (ei[2*i+1] != 0) all0 = 0;
            *flag = all0;   // 1 => data is int64, read low words
        }
    }
}

// ---------- mega: dense GEMM tiles (blocks 0..GEMMB-1) + edge-bucket fill ----------
// The GEMM path is latency-bound with idle pipes (r14 PMC: VALU 11%, MFMA 7%,
// HBM 19%); the fill path (independent dataflow: edge data only) rides in its
// latency bubbles instead of serializing as a separate 8 us dispatch.
__global__ __launch_bounds__(256, 4) void k_mega(
    const float* __restrict__ z1,
    const float* __restrict__ sa_w, const float* __restrict__ sa_bp,
    const unsigned short* __restrict__ Bpack,
    float* __restrict__ S, unsigned short* __restrict__ Y,
    const int* __restrict__ ei, const float* __restrict__ ew,
    const int* __restrict__ flag, int* __restrict__ fill, int4* __restrict__ bkt)
{
    __shared__ __align__(16) unsigned short tileA[64][260];  // stride 520B: conflict-free A reads

    if (blockIdx.x >= GEMMB){
        // ---- fill path: stage (col, weight, eid) per row as one int4 store ----
        int e = (blockIdx.x - GEMMB)*256 + threadIdx.x;
        if (e < EE){
            int f = *flag;
            int r = e_row(ei, f, e);
            int c = e_col(ei, f, e);
            int pos = atomicAdd(&fill[r], 1);
            if (pos < BCAP){
                int4 v; v.x = c; v.y = __float_as_int(ew[e]); v.z = e; v.w = 0;
                bkt[r*BCAP + pos] = v;
            }
        }
        return;
    }

    // ---- GEMM path (round-8/11 proven config): S = z1·sa_w + b ; Y = bf16(z1) @ lin_w^T
    // 4 waves share one 64x260 A-tile; wave w owns 64 output cols x all 64 rows.
    // Single-buffered B (dbuf spills, r10); occupancy is not the limiter (r12).
    const int tid = threadIdx.x, wave = tid >> 6, lane = tid & 63;
    const int r0 = blockIdx.x*64;
    const int rw = r0 + wave*16;            // this wave stages rows rw..rw+15

    // stage 1: all 16 row-loads issued up-front (one vmcnt batch), then S + bf16 tile
    {
        const float4 sw = *(const float4*)&sa_w[lane*4];
        const float sab = *sa_bp;
        float4 v[16];
        #pragma unroll
        for (int rl = 0; rl < 16; ++rl)
            v[rl] = *(const float4*)&z1[(size_t)(rw+rl)*DD + lane*4];
        #pragma unroll
        for (int rl = 0; rl < 16; ++rl){
            float p = dot4(v[rl], sw);
            #pragma unroll
            for (int o = 32; o > 0; o >>= 1) p += __shfl_xor(p, o, 64);
            if (lane == 0) S[rw+rl] = p + sab;
            ushort4 u;
            u.x = f2bf(v[rl].x); u.y = f2bf(v[rl].y);
            u.z = f2bf(v[rl].z); u.w = f2bf(v[rl].w);
            *(ushort4*)&tileA[wave*16 + rl][lane*4] = u;
        }
    }
    __syncthreads();

    // stage 2: 16x16x32 MFMA. A: row=lane&15, k=(lane>>4)*8+i ;
    // C/D: col=lane&15, row=(lane>>4)*4+reg. acc[rf][nj], nt = wave*4+nj.
    const unsigned short* aBase = &tileA[lane & 15][(lane >> 4) * 8];
    const short8* bPtr = (const short8*)Bpack + lane;
    f32x4 acc[4][4];
    #pragma unroll
    for (int rf = 0; rf < 4; ++rf)
        #pragma unroll
        for (int nj = 0; nj < 4; ++nj) acc[rf][nj] = (f32x4){0.f,0.f,0.f,0.f};

    #pragma unroll
    for (int ks = 0; ks < 8; ++ks){
        short8 bfr[4];
        #pragma unroll
        for (int nj = 0; nj < 4; ++nj)
            bfr[nj] = bPtr[((wave*4 + nj)*8 + ks)*64];
        #pragma unroll
        for (int rf = 0; rf < 4; ++rf){
            const short8 a = *(const short8*)(aBase + rf*16*260 + ks*32);
            #pragma unroll
            for (int nj = 0; nj < 4; ++nj)
                acc[rf][nj] = __builtin_amdgcn_mfma_f32_16x16x32_bf16(a, bfr[nj], acc[rf][nj], 0, 0, 0);
        }
    }

    // store raw Y (no bias/norm here; bias folds through the attention sum)
    #pragma unroll
    for (int rf = 0; rf < 4; ++rf){
        const int rowBase = r0 + rf*16 + (lane >> 4)*4;
        #pragma unroll
        for (int nj = 0; nj < 4; ++nj){
            const int col = (wave*4 + nj)*16 + (lane & 15);
            #pragma unroll
            for (int reg = 0; reg < 4; ++reg)
                Y[(size_t)(rowBase + reg)*DD + col] = f2bf(acc[rf][nj][reg]);
        }
    }
}

// One WAVE per row: dedup (max eid wins per (r,c) = numpy last-write-wins),
// drop diagonal edges and w<=0, rank by (w desc, c asc) = lax.top_k order.
__global__ __launch_bounds__(256) void k_top5(
    const int* __restrict__ fill, const int4* __restrict__ bkt,
    int* __restrict__ nbr_idx, int* __restrict__ nbr_cnt)
{
    const int wave = threadIdx.x >> 6, lane = threadIdx.x & 63;
    const int r = blockIdx.x*4 + wave;
    if (r >= NN) return;
    int cnt = fill[r]; if (cnt > BCAP) cnt = BCAP;

    int c = -1, e = -1; float w = 0.f;
    if (lane < cnt){
        const int4 v = bkt[r*BCAP + lane];
        c = v.x; w = __int_as_float(v.y); e = v.z;
    }
    bool alive = (lane < cnt) && (c != r) && (w > 0.f);

    for (int j = 0; j < cnt; ++j){
        const int cj = __shfl(c, j, 64);
        const int ej = __shfl(e, j, 64);
        if (cj == c && ej > e) alive = false;
    }
    int rank = 0;
    const int av = alive ? 1 : 0;
    for (int j = 0; j < cnt; ++j){
        const int   aj = __shfl(av, j, 64);
        const float wj = __shfl(w,  j, 64);
        const int   cj = __shfl(c,  j, 64);
        if (aj && (wj > w || (wj == w && cj < c))) ++rank;
    }
    const int want = lane - 1;
    int val = r;
    for (int j = 0; j < cnt; ++j){
        const int aj = __shfl(av,   j, 64);
        const int rj = __shfl(rank, j, 64);
        const int cj = __shfl(c,    j, 64);
        if (aj && rj == want && rj < 4) val = cj;
    }
    if (lane < KK) nbr_idx[r*KK + lane] = val;
    if (lane == 0){
        const int na = __popcll(__ballot(alive));
        nbr_cnt[r] = 1 + (na < 4 ? na : 4);
    }
}

// ---------- pair-fused softmax + gather + loss, one pair per HALF-wave ----------
// sigma(b,n) = (b^1, (n+5000)%NN) is a fixed-point-free involution.
// Softmax computed in-place: lanes hl 0-7 own row0's k-slots, hl 8-15 row1's
// (3-step shfl group-reduce); a_k broadcast by __shfl in the gather loop.
// Invalid k slots get exp(-1e9 - m) = 0 (exactly the reference NEG_INF mask).
// XCD-aware chunked block swizzle (bijective for 2500 = 4*313 + 4*312):
// consecutive logical blocks share the same batch-pair's Y slabs; chunking
// keeps each XCD's gathers within ~2 slabs -> local-L2 hits on ~5x reuse.
__global__ __launch_bounds__(256) void k_aggred(
    const float* __restrict__ z2, const unsigned short* __restrict__ Y,
    const float* __restrict__ S,
    const int* __restrict__ nbr_idx, const int* __restrict__ nbr_cnt,
    const float* __restrict__ lin_b,
    double* __restrict__ loss_part, long long* __restrict__ cnt_part)
{
    const int tid = threadIdx.x;
    const int wave = tid >> 6, lane = tid & 63;
    const int half = lane >> 5, hl = lane & 31;
    // bijective XCD chunking: physical bid -> logical swz
    const unsigned bid = blockIdx.x;
    const unsigned xcd = bid & 7u, idx = bid >> 3;
    const unsigned swz = (xcd < 4u ? xcd*313u : 4u*313u + (xcd-4u)*312u) + idx;
    const int gw = (int)swz*4 + wave;            // 0..9999
    const int cb = hl*8;                         // this lane's 8-col slice
    const float4 lba = *(const float4*)&lin_b[cb];
    const float4 lbb = *(const float4*)&lin_b[cb+4];
    double lacc = 0.0;
    int cacc = 0;

    #pragma unroll 1
    for (int j = 0; j < 2; ++j){
        const int p  = gw*4 + j*2 + half;        // 0..39999, unique per half-wave
        const int bb = p / NN, n0 = p % NN;
        const int b0 = 2*bb, b1 = b0 + 1;
        int n1 = n0 + 5000; if (n1 >= NN) n1 -= NN;
        const size_t r0 = (size_t)b0*NN + n0;
        const size_t r1 = (size_t)b1*NN + n1;

        // in-place softmax: hl 0-7 = row0 slots, hl 8-15 = row1 slots
        const int cnt0 = nbr_cnt[n0], cnt1 = nbr_cnt[n1];
        float sv = -1e9f;
        if (hl < 8){
            if (hl < cnt0) sv = S[b0*NN + nbr_idx[n0*KK + hl]];
        } else if (hl < 16){
            const int k2 = hl - 8;
            if (k2 < cnt1) sv = S[b1*NN + nbr_idx[n1*KK + k2]];
        }
        float mx = sv;
        #pragma unroll
        for (int o = 1; o < 8; o <<= 1) mx = fmaxf(mx, __shfl_xor(mx, o, 64));
        const float ev = __expf(sv - mx);
        float sm = ev;
        #pragma unroll
        for (int o = 1; o < 8; o <<= 1) sm += __shfl_xor(sm, o, 64);
        const float av = ev / sm;                // softmax weight on slot lanes

        float4 h0a = lba, h0b = lbb, h1a = lba, h1b = lbb;
        #pragma unroll
        for (int k = 0; k < KK; ++k){
            const int i0 = nbr_idx[n0*KK + k];
            const int i1 = nbr_idx[n1*KK + k];
            const float a0 = __shfl(av, half*32 + k, 64);
            const float a1 = __shfl(av, half*32 + 8 + k, 64);
            const uint4 u0 = *(const uint4*)&Y[((size_t)(b0*NN) + i0)*DD + cb];
            const uint4 u1 = *(const uint4*)&Y[((size_t)(b1*NN) + i1)*DD + cb];
            h0a.x = fmaf(a0, bflo(u0.x), h0a.x); h0a.y = fmaf(a0, bfhi(u0.x), h0a.y);
            h0a.z = fmaf(a0, bflo(u0.y), h0a.z); h0a.w = fmaf(a0, bfhi(u0.y), h0a.w);
            h0b.x = fmaf(a0, bflo(u0.z), h0b.x); h0b.y = fmaf(a0, bfhi(u0.z), h0b.y);
            h0b.z = fmaf(a0, bflo(u0.w), h0b.z); h0b.w = fmaf(a0, bfhi(u0.w), h0b.w);
            h1a.x = fmaf(a1, bflo(u1.x), h1a.x); h1a.y = fmaf(a1, bfhi(u1.x), h1a.y);
            h1a.z = fmaf(a1, bflo(u1.y), h1a.z); h1a.w = fmaf(a1, bfhi(u1.y), h1a.w);
            h1b.x = fmaf(a1, bflo(u1.z), h1b.x); h1b.y = fmaf(a1, bfhi(u1.z), h1b.y);
            h1b.z = fmaf(a1, bflo(u1.w), h1b.z); h1b.w = fmaf(a1, bfhi(u1.w), h1b.w);
        }
        const float4 s0a = *(const float4*)&z2[r0*DD + cb];
        const float4 s0b = *(const float4*)&z2[r0*DD + cb + 4];
        const float4 s1a = *(const float4*)&z2[r1*DD + cb];
        const float4 s1b = *(const float4*)&z2[r1*DD + cb + 4];

        float d0 = dot4(s0a,s0a) + dot4(s0b,s0b);
        float d1 = dot4(s1a,s1a) + dot4(s1b,s1b);
        float d2 = dot4(h0a,h0a) + dot4(h0b,h0b);
        float d3 = dot4(h1a,h1a) + dot4(h1b,h1b);
        float d4 = dot4(s0a,h0a) + dot4(s0b,h0b);
        float d5 = dot4(s1a,h1a) + dot4(s1b,h1b);
        float d6 = dot4(s0a,h1a) + dot4(s0b,h1b);
        float d7 = dot4(s1a,h0a) + dot4(s1b,h0b);
        #pragma unroll
        for (int o = 1; o < 32; o <<= 1){        // 5-step butterfly within the half
            d0 += __shfl_xor(d0, o, 64);
            d1 += __shfl_xor(d1, o, 64);
            d2 += __shfl_xor(d2, o, 64);
            d3 += __shfl_xor(d3, o, 64);
            d4 += __shfl_xor(d4, o, 64);
            d5 += __shfl_xor(d5, o, 64);
            d6 += __shfl_xor(d6, o, 64);
            d7 += __shfl_xor(d7, o, 64);
        }
        // hl 0: x0=d4/sqrt(d0*d2) real ; hl 1: x1=d5/sqrt(d1*d3) real
        // hl 2: y0=d6/sqrt(d0*d3) fake ; hl 3: y1=d7/sqrt(d1*d2) fake
        const float num = hl==1 ? d5 : (hl==2 ? d6 : (hl==3 ? d7 : d4));
        const float den = hl==1 ? d1*d3 : (hl==2 ? d0*d3 : (hl==3 ? d1*d2 : d0*d2));
        if (hl < 4){
            const bool real = (hl < 2);
            const float x = num * rsqrtf(den);
            const float z = __expf(-fabsf(x));            // |x|<=1 -> z in [0.37,1]
            const float l = fmaxf(x, 0.f) - (real ? x : 0.f) + __logf(1.f + z);
            lacc += (double)l;
            cacc += real ? (x > 0.f ? 1 : 0) : (x > 0.f ? 0 : 1);
        }
    }
    // reduce lanes {0-3} and {32-35} -> lane 0
    lacc += __shfl_xor(lacc, 1, 64);
    lacc += __shfl_xor(lacc, 2, 64);
    lacc += __shfl_xor(lacc, 32, 64);
    cacc += __shfl_xor(cacc, 1, 64);
    cacc += __shfl_xor(cacc, 2, 64);
    cacc += __shfl_xor(cacc, 32, 64);

    __shared__ double sl[4];
    __shared__ int scn[4];
    if (lane == 0){ sl[wave] = lacc; scn[wave] = cacc; }
    __syncthreads();
    if (tid == 0){
        loss_part[blockIdx.x] = sl[0]+sl[1]+sl[2]+sl[3];
        cnt_part[blockIdx.x]  = (long long)scn[0] + scn[1] + scn[2] + scn[3];
    }
}

__global__ void k_final(const double* __restrict__ loss_part,
                        const long long* __restrict__ cnt_part,
                        float* __restrict__ out){
    __shared__ double sl[256];
    __shared__ long long sc[256];
    double l = 0.0; long long c = 0;
    for (int i = threadIdx.x; i < AGGB; i += 256){ l += loss_part[i]; c += cnt_part[i]; }
    sl[threadIdx.x] = l; sc[threadIdx.x] = c;
    __syncthreads();
    for (int s = 128; s > 0; s >>= 1){
        if (threadIdx.x < s){
            sl[threadIdx.x] += sl[threadIdx.x + s];
            sc[threadIdx.x] += sc[threadIdx.x + s];
        }
        __syncthreads();
    }
    if (threadIdx.x == 0){
        const double denom = 2.0 * BSZ * NN;   // 160000
        out[0] = (float)(sl[0] / denom);
        out[1] = (float)((double)sc[0] / denom);
    }
}

// ---------- host ----------
extern "C" void kernel_launch(void* const* d_in, const int* in_sizes, int n_in,
                              void* d_out, int out_size, void* d_ws, size_t ws_size,
                              hipStream_t stream)
{
    (void)in_sizes; (void)n_in; (void)out_size; (void)ws_size;
    const float* z1    = (const float*)d_in[0];
    const float* z2    = (const float*)d_in[1];
    const int*   ei    = (const int*)d_in[2];
    const float* ew    = (const float*)d_in[3];
    const float* sa_w  = (const float*)d_in[4];
    const float* sa_b  = (const float*)d_in[5];
    const float* lin_w = (const float*)d_in[6];
    const float* lin_b = (const float*)d_in[7];
    float* out = (float*)d_out;

    char* ws = (char*)d_ws;
    size_t off = 0;
    auto take = [&](size_t bytes) -> char* {
        char* p = ws + off;
        off = (off + bytes + 255) & ~(size_t)255;
        return p;
    };
    int*            flag      = (int*)take(4);
    int*            fill      = (int*)take((size_t)NN*4);
    int*            nbr_idx   = (int*)take((size_t)NN*KK*4);
    int*            nbr_cnt   = (int*)take((size_t)NN*4);
    unsigned short* Bpack     = (unsigned short*)take((size_t)16*8*64*8*2);
    float*          S         = (float*)take((size_t)NROW*4);
    double*         loss_part = (double*)take((size_t)AGGB*8);
    long long*      cnt_part  = (long long*)take((size_t)AGGB*8);
    // bkt can NOT overlay Y: fill and gemm run concurrently in k_mega.
    int4*           bkt       = (int4*)take((size_t)NN*BCAP*16);   // 10.24 MB
    unsigned short* Y         = (unsigned short*)take((size_t)NROW*DD*2);  // 40.96 MB

    k_setup <<<72,            256, 0, stream>>>(lin_w, Bpack, ei, fill, flag);
    k_mega  <<<GEMMB + FILLB, 256, 0, stream>>>(z1, sa_w, sa_b, Bpack, S, Y,
                                                ei, ew, flag, fill, bkt);
    k_top5  <<<(NN+3)/4,      256, 0, stream>>>(fill, bkt, nbr_idx, nbr_cnt);
    k_aggred<<<AGGB,          256, 0, stream>>>(z2, Y, S, nbr_idx, nbr_cnt, lin_b,
                                                loss_part, cnt_part);
    k_final <<<1,             256, 0, stream>>>(loss_part, cnt_part, out);
}